// Round 11
// baseline (573.493 us; speedup 1.0000x reference)
//
#include <hip/hip_runtime.h>
#include <hip/hip_fp16.h>
#include <stdint.h>

// SelfAttention: out = softmax((X Wq)(X Wk)^T / 32) (X Wv), N=8192, D=1024.
// R11: register-level software pipeline. Counter evidence (4 schedule nulls):
//      LDS-read time + MFMA time SUM per K-tile (PV: 2483+2690 = 5175 cyc
//      measured) because reads and MFMAs of the same phase serialize within
//      barrier-locked waves. Fix: each quarter issues the NEXT quarter's
//      ds_reads (spare reg set), then MFMAs the current one -> LDS pipe works
//      under the MFMA cluster. Tile-invariant register roles; publish
//      boundary between q2/q3. No extra frag VGPRs (fp16), +32 (i8).

typedef _Float16 half_t;
typedef _Float16 half8 __attribute__((ext_vector_type(8)));
typedef _Float16 half4 __attribute__((ext_vector_type(4)));
typedef float f32x4 __attribute__((ext_vector_type(4)));
typedef int i32x4 __attribute__((ext_vector_type(4)));

#define GLOAD16(gp, lp)                                                        \
  __builtin_amdgcn_global_load_lds(                                            \
      (__attribute__((address_space(1))) void*)(gp),                           \
      (__attribute__((address_space(3))) void*)(lp), 16, 0, 0)

#define BAR() __builtin_amdgcn_s_barrier()
#define SCHED0() __builtin_amdgcn_sched_barrier(0)
#define LGKM0() asm volatile("s_waitcnt lgkmcnt(0)")
#define VMCNT8() asm volatile("s_waitcnt vmcnt(8)")
#define VMCNT4() asm volatile("s_waitcnt vmcnt(4)")
#define VMCNT0() asm volatile("s_waitcnt vmcnt(0)")

// ---------------------------------------------------------------- cast X
__global__ __launch_bounds__(256) void cast_f32_to_f16(
    const float* __restrict__ in, half_t* __restrict__ out, int n4) {
  int i = blockIdx.x * 256 + threadIdx.x;
  if (i < n4) {
    float4 v = ((const float4*)in)[i];
    half4 o = {(half_t)v.x, (half_t)v.y, (half_t)v.z, (half_t)v.w};
    ((half4*)out)[i] = o;
  }
}

// ------------------------------------------------- cast + transpose (any->fp16)
template <typename Tin>
__global__ __launch_bounds__(256) void transpose_cast(
    const Tin* __restrict__ in, int ldin, half_t* __restrict__ out, int ldout,
    int R, int C) {
  __shared__ half_t tile[64][65];
  const int c0 = blockIdx.x * 64, r0 = blockIdx.y * 64;
  const int tx = threadIdx.x & 63, ty = threadIdx.x >> 6;
#pragma unroll
  for (int i = 0; i < 16; i++) {
    int r = ty * 16 + i;
    tile[r][tx] = (half_t)in[(size_t)(r0 + r) * ldin + c0 + tx];
  }
  __syncthreads();
#pragma unroll
  for (int i = 0; i < 16; i++) {
    int c = ty * 16 + i;
    out[(size_t)(c0 + c) * ldout + r0 + tx] = tile[tx][c];
  }
}

// ---------------------------------------------------------- rowsum reciprocal
__global__ __launch_bounds__(256) void rowsum_recip(
    const float* __restrict__ rowpart, float* __restrict__ rinv, int rows,
    int w4) {
  int r = blockIdx.x * 256 + threadIdx.x;
  if (r < rows) {
    const float4* p = (const float4*)(rowpart + (size_t)r * (w4 * 4));
    float s = 0.f;
    for (int i = 0; i < w4; i++) {
      float4 v = p[i];
      s += v.x + v.y + v.z + v.w;
    }
    rinv[r] = 1.f / s;
  }
}

// ------------------------------------------------- reduce (fp16 partials add)
__global__ __launch_bounds__(256) void reduce_add2h(
    const half8* __restrict__ a, const half8* __restrict__ b,
    float4* __restrict__ o, int n8) {
  int i = blockIdx.x * 256 + threadIdx.x;
  if (i < n8) {
    half8 x = a[i], y = b[i];
    float4 o0, o1;
    o0.x = (float)x[0] + (float)y[0];
    o0.y = (float)x[1] + (float)y[1];
    o0.z = (float)x[2] + (float)y[2];
    o0.w = (float)x[3] + (float)y[3];
    o1.x = (float)x[4] + (float)y[4];
    o1.y = (float)x[5] + (float)y[5];
    o1.z = (float)x[6] + (float)y[6];
    o1.w = (float)x[7] + (float)y[7];
    o[2 * i] = o0;
    o[2 * i + 1] = o1;
  }
}

// ============================================================ fp16 256^2 GEMM
// MODE 2: QKV fused output — bx<4: Qi8, bx<8: Ki8 (scale 32), bx>=8: Vh fp16.
// MODE 3: PV — write (acc*rinv[r]) fp16.
// Quarter pipeline per K-tile (BK=64, quarters (k0m0,k0m1,k1m0,k1m1)):
//   q: issue next quarter's ds_reads -> spare set; sched_barrier; 16 MFMA.
//   boundary between q2/q3: lgkm0+BAR; stage(t+2->cb); vmcnt(8); BAR.
template <typename To, int MODE>
__global__ __launch_bounds__(512, 2) void gemm256(
    const half_t* __restrict__ A, int lda, const half_t* __restrict__ Bt,
    int ldb, To* __restrict__ C, int ldc, int M, int N, int K, int ychunks,
    int SG, const float* __restrict__ rinv, int8_t* __restrict__ qi8,
    int8_t* __restrict__ ki8) {
  __shared__ __align__(16) char sm[131072];

  const int t = threadIdx.x;
  const int w = t >> 6;
  const int ln = t & 63;

  const int nwg = gridDim.x * gridDim.y;
  const int bid = blockIdx.y * gridDim.x + blockIdx.x;
  const int cpx = nwg >> 3;
  const int q = (bid & 7) * cpx + (bid >> 3);
  const int tiles_y = gridDim.y / ychunks;
  const int per_chunk = gridDim.x * tiles_y;
  const int chunk = q / per_chunk;
  int r_ = q - chunk * per_chunk;
  const int sw = SG * tiles_y;
  const int s_ = r_ / sw;
  r_ -= s_ * sw;
  const int by = r_ / SG;
  const int bx = s_ * SG + (r_ - by * SG);

  A += (size_t)chunk * K;
  Bt += (size_t)chunk * K;
  C += (size_t)chunk * M * ldc;

  const int row0 = by * 256;
  const int col0 = bx * 256;

  const int srow = w * 8 + (ln >> 3);
  const int sslot = (ln & 7) ^ ((ln >> 3) & 7);
  const half_t* Ag = A + (size_t)(row0 + srow) * lda + sslot * 8;
  const half_t* Bg = Bt + (size_t)(col0 + srow) * ldb + sslot * 8;
  const int ldsw = w * 1024;

#define STAGE_AB(kt, bb)                                                       \
  do {                                                                         \
    const half_t* ga_ = Ag + (size_t)(kt) * 64;                                \
    const half_t* gb_ = Bg + (size_t)(kt) * 64;                                \
    GLOAD16(ga_, sm + (bb) + ldsw);                                            \
    GLOAD16(ga_ + 64 * (size_t)lda, sm + (bb) + 8192 + ldsw);                  \
    GLOAD16(ga_ + 128 * (size_t)lda, sm + (bb) + 16384 + ldsw);                \
    GLOAD16(ga_ + 192 * (size_t)lda, sm + (bb) + 24576 + ldsw);                \
    GLOAD16(gb_, sm + (bb) + 32768 + ldsw);                                    \
    GLOAD16(gb_ + 64 * (size_t)ldb, sm + (bb) + 40960 + ldsw);                 \
    GLOAD16(gb_ + 128 * (size_t)ldb, sm + (bb) + 49152 + ldsw);                \
    GLOAD16(gb_ + 192 * (size_t)ldb, sm + (bb) + 57344 + ldsw);                \
  } while (0)

  const int wr = w >> 2;
  const int wc = w & 3;
  const int fr = ln & 15;
  const int kg = ln >> 4;
  const int sx0 = ((kg ^ (fr & 7)) << 4);
  const int sx1 = sx0 ^ 64;
  const int arow = (wr * 128 + fr) * 128;
  const int brow = 32768 + (wc * 64 + fr) * 128;

#define RD_A(dst, MI0, cb, SX)                                                 \
  _Pragma("unroll") for (int mi = 0; mi < 4; mi++) dst[mi] =                   \
      *(const half8*)(sm + (cb) + arow + ((MI0) + mi) * 2048 + (SX));
#define RD_B(dst, cb, SX)                                                      \
  _Pragma("unroll") for (int ni = 0; ni < 4; ni++) dst[ni] =                   \
      *(const half8*)(sm + (cb) + brow + ni * 2048 + (SX));

#define MM16(MI0, As, Bs)                                                      \
  __builtin_amdgcn_s_setprio(1);                                               \
  _Pragma("unroll") for (int mi = 0; mi < 4; mi++)                             \
  _Pragma("unroll") for (int ni = 0; ni < 4; ni++)                             \
      acc[(MI0) + mi][ni] = __builtin_amdgcn_mfma_f32_16x16x32_f16(            \
          As[mi], Bs[ni], acc[(MI0) + mi][ni], 0, 0, 0);                       \
  __builtin_amdgcn_s_setprio(0);

  half8 Aa[4], Ab[4], Bb0[4], Bb1[4];
  f32x4 acc[8][4] = {};

  const int NT = K >> 6;

  // prologue: tile0 -> buf0, tile1 -> buf1; wait tile0; preload (k0,m0)+B(k0)
  STAGE_AB(0, 0);
  STAGE_AB(1, 65536);
  VMCNT8();
  BAR();
  RD_A(Aa, 0, 0, sx0);
  RD_B(Bb0, 0, sx0);

// Register roles are tile-invariant:
//   Aa: (k0,m0)->consumed q0, reloaded q1 with (k1,m0); Ab: (k0,m1)/(k1,m1);
//   Bb0: B(k0) (q0,q1), reloaded q3 with next tile's B(k0); Bb1: B(k1) (q2,q3).
#define TILE(tt, cb)                                                           \
  do {                                                                         \
    /* q0: (k0,m0) */                                                          \
    RD_A(Ab, 4, cb, sx0);                                                      \
    SCHED0();                                                                  \
    MM16(0, Aa, Bb0);                                                          \
    /* q1: (k0,m1) */                                                          \
    RD_A(Aa, 0, cb, sx1);                                                      \
    RD_B(Bb1, cb, sx1);                                                        \
    SCHED0();                                                                  \
    MM16(4, Ab, Bb0);                                                          \
    /* q2: (k1,m0) */                                                          \
    RD_A(Ab, 4, cb, sx1);                                                      \
    SCHED0();                                                                  \
    MM16(0, Aa, Bb1);                                                          \
    /* boundary: all cb reads done -> republish cb with tile t+2 */            \
    LGKM0();                                                                   \
    BAR();                                                                     \
    if ((tt) + 2 < NT) {                                                       \
      STAGE_AB((tt) + 2, cb);                                                  \
      VMCNT8();                                                                \
    } else {                                                                   \
      VMCNT0();                                                                \
    }                                                                          \
    BAR();                                                                     \
    /* q3: (k1,m1); prefetch next tile's (k0,m0)+B(k0) from cb^1 */            \
    if ((tt) + 1 < NT) {                                                       \
      RD_A(Aa, 0, (cb) ^ 65536, sx0);                                          \
      RD_B(Bb0, (cb) ^ 65536, sx0);                                            \
    }                                                                          \
    SCHED0();                                                                  \
    MM16(4, Ab, Bb1);                                                          \
  } while (0)

  for (int kt = 0; kt < NT; kt += 2) {
    TILE(kt, 0);
    TILE(kt + 1, 65536);
  }

  // ---- epilogue: C/D layout col = lane&15, row = (lane>>4)*4 + j ----
  const int orow = row0 + wr * 128 + (ln >> 4) * 4;
  const int ocol = col0 + wc * 64 + (ln & 15);
  if constexpr (MODE == 2) {
    if (bx < 8) {  // Q or K region -> i8 only (scale 32)
      int8_t* qk = bx < 4 ? qi8 : ki8;
      const int cbase = ocol - (bx < 4 ? 0 : 1024);
#pragma unroll
      for (int mi = 0; mi < 8; mi++)
#pragma unroll
        for (int j = 0; j < 4; j++) {
          const size_t r = orow + mi * 16 + j;
#pragma unroll
          for (int ni = 0; ni < 4; ni++) {
            float f = acc[mi][ni][j] * 32.f;
            f = fminf(fmaxf(f, -127.f), 127.f);
            qk[r * 1024 + cbase + ni * 16] = (int8_t)rintf(f);
          }
        }
    } else {  // V region -> fp16 (C = Vh, ldc = 1024)
      const int cbase = ocol - 2048;
#pragma unroll
      for (int mi = 0; mi < 8; mi++)
#pragma unroll
        for (int ni = 0; ni < 4; ni++) {
          To* cp = C + (size_t)(orow + mi * 16) * ldc + cbase + ni * 16;
#pragma unroll
          for (int j = 0; j < 4; j++) cp[(size_t)j * ldc] = (To)acc[mi][ni][j];
        }
    }
  } else if constexpr (MODE == 3) {
#pragma unroll
    for (int mi = 0; mi < 8; mi++)
#pragma unroll
      for (int j = 0; j < 4; j++) {
        const size_t r = orow + mi * 16 + j;
        const float s = rinv[r];
#pragma unroll
        for (int ni = 0; ni < 4; ni++)
          C[r * ldc + ocol + ni * 16] = (To)(acc[mi][ni][j] * s);
      }
  } else {
#pragma unroll
    for (int mi = 0; mi < 8; mi++)
#pragma unroll
      for (int ni = 0; ni < 4; ni++) {
        To* cp = C + (size_t)(orow + mi * 16) * ldc + ocol + ni * 16;
#pragma unroll
        for (int j = 0; j < 4; j++) cp[(size_t)j * ldc] = (To)acc[mi][ni][j];
      }
  }
#undef TILE
#undef MM16
#undef RD_A
#undef RD_B
#undef STAGE_AB
}

// ============================================================ i8 256^2 S-GEMM
// P' = exp((A i8dot Bt) * 2^-15) fp16 + row partials.  Half pipeline per
// K-tile (halves m0-3 / m4-7, single k-slice K=64). B sets alternate by tile
// parity (Bc consumed both halves; Bn loaded at h1 from next buffer).
__global__ __launch_bounds__(512, 2) void gemm256_i8exp(
    const int8_t* __restrict__ A, int lda, const int8_t* __restrict__ Bt,
    int ldb, half_t* __restrict__ C, int ldc, int K, int SG,
    float* __restrict__ rowpart) {
  __shared__ __align__(16) char sm[65536];

  const int t = threadIdx.x;
  const int w = t >> 6;
  const int ln = t & 63;

  const int nwg = gridDim.x * gridDim.y;
  const int bid = blockIdx.y * gridDim.x + blockIdx.x;
  const int cpx = nwg >> 3;
  const int q = (bid & 7) * cpx + (bid >> 3);
  const int sw = SG * gridDim.y;
  const int s_ = q / sw;
  int r_ = q - s_ * sw;
  const int by = r_ / SG;
  const int bx = s_ * SG + (r_ - by * SG);

  const int row0 = by * 256;
  const int col0 = bx * 256;

  const int rt = w * 16 + (ln >> 2);
  const int sl = (ln & 3) ^ ((rt >> 1) & 3);
  const int8_t* Ag = A + (size_t)(row0 + rt) * lda + sl * 16;
  const int8_t* Bg = Bt + (size_t)(col0 + rt) * ldb + sl * 16;
  const int ldsw = w * 1024;

#define STAGE8(kt, bb)                                                         \
  do {                                                                         \
    const int8_t* ga_ = Ag + (size_t)(kt) * 64;                                \
    const int8_t* gb_ = Bg + (size_t)(kt) * 64;                                \
    GLOAD16(ga_, sm + (bb) + ldsw);                                            \
    GLOAD16(ga_ + 128 * (size_t)lda, sm + (bb) + 8192 + ldsw);                 \
    GLOAD16(gb_, sm + (bb) + 16384 + ldsw);                                    \
    GLOAD16(gb_ + 128 * (size_t)ldb, sm + (bb) + 24576 + ldsw);                \
  } while (0)

  const int wr = w >> 2;
  const int wc = w & 3;
  const int fr = ln & 15;
  const int kg = ln >> 4;
  const int sx = (kg ^ ((fr >> 1) & 3)) << 4;
  const int arow = (wr * 128 + fr) * 64;
  const int brow = 16384 + (wc * 64 + fr) * 64;

#define RD_A8(dst, MI0, cb)                                                    \
  _Pragma("unroll") for (int mi = 0; mi < 4; mi++) dst[mi] =                   \
      *(const i32x4*)(sm + (cb) + arow + ((MI0) + mi) * 1024 + sx);
#define RD_B8(dst, cb)                                                         \
  _Pragma("unroll") for (int ni = 0; ni < 4; ni++) dst[ni] =                   \
      *(const i32x4*)(sm + (cb) + brow + ni * 1024 + sx);

#define MM16_8(MI0, As, Bs)                                                    \
  __builtin_amdgcn_s_setprio(1);                                               \
  _Pragma("unroll") for (int mi = 0; mi < 4; mi++)                             \
  _Pragma("unroll") for (int ni = 0; ni < 4; ni++)                             \
      acc[(MI0) + mi][ni] = __builtin_amdgcn_mfma_i32_16x16x64_i8(             \
          As[mi], Bs[ni], acc[(MI0) + mi][ni], 0, 0, 0);                       \
  __builtin_amdgcn_s_setprio(0);

  i32x4 Aa8[4], Ab8[4], B0s[4], B1s[4];
  i32x4 acc[8][4] = {};

  const int NT = K >> 6;  // 16

  // prologue
  STAGE8(0, 0);
  STAGE8(1, 32768);
  VMCNT4();
  BAR();
  RD_A8(Aa8, 0, 0);
  RD_B8(B0s, 0);

#define TILE8(tt, cb, Bc, Bn)                                                  \
  do {                                                                         \
    /* h0: m0-3 */                                                             \
    RD_A8(Ab8, 4, cb);                                                         \
    SCHED0();                                                                  \
    MM16_8(0, Aa8, Bc);                                                        \
    /* boundary */                                                             \
    LGKM0();                                                                   \
    BAR();                                                                     \
    if ((tt) + 2 < NT) {                                                       \
      STAGE8((tt) + 2, cb);                                                    \
      VMCNT4();                                                                \
    } else {                                                                   \
      VMCNT0();                                                                \
    }                                                                          \
    BAR();                                                                     \
    /* h1: m4-7; prefetch next tile's A(m0-3)+B from cb^1 */                   \
    if ((tt) + 1 < NT) {                                                       \
      RD_A8(Aa8, 0, (cb) ^ 32768);                                             \
      RD_B8(Bn, (cb) ^ 32768);                                                 \
    }                                                                          \
    SCHED0();                                                                  \
    MM16_8(4, Ab8, Bc);                                                        \
  } while (0)

  for (int kt = 0; kt < NT; kt += 2) {
    TILE8(kt, 0, B0s, B1s);
    TILE8(kt + 1, 32768, B1s, B0s);
  }

  // ---- epilogue: s = acc * 2^-15 (scale 32*32 quant, /32 softmax) ----
  const int orow = row0 + wr * 128 + (ln >> 4) * 4;
  const int ocol = col0 + wc * 64 + (ln & 15);
  const float sc = 3.0517578125e-5f;  // 1/32768
  const int rp_ld = gridDim.x * 4;
#pragma unroll
  for (int mi = 0; mi < 8; mi++) {
#pragma unroll
    for (int j = 0; j < 4; j++) {
      const int r = orow + mi * 16 + j;
      float s = 0.f;
#pragma unroll
      for (int ni = 0; ni < 4; ni++) {
        float e = __expf((float)acc[mi][ni][j] * sc);
        C[(size_t)r * ldc + ocol + ni * 16] = (half_t)e;
        s += e;
      }
      s += __shfl_xor(s, 1);
      s += __shfl_xor(s, 2);
      s += __shfl_xor(s, 4);
      s += __shfl_xor(s, 8);
      if ((ln & 15) == 0) rowpart[(size_t)r * rp_ld + bx * 4 + wc] = s;
    }
  }
#undef TILE8
#undef MM16_8
#undef RD_A8
#undef RD_B8
#undef STAGE8
}

// ---------------------------------------------------------------- launch
extern "C" void kernel_launch(void* const* d_in, const int* in_sizes, int n_in,
                              void* d_out, int out_size, void* d_ws,
                              size_t ws_size, hipStream_t stream) {
  const float* X = (const float*)d_in[0];
  const float* Wq = (const float*)d_in[1];
  const float* Wk = (const float*)d_in[2];
  const float* Wv = (const float*)d_in[3];
  float* out = (float*)d_out;

  const int N = 8192, D = 1024;

  char* ws = (char*)d_ws;
  half_t* Xh   = (half_t*)(ws);                   // [0,16)
  half_t* Wth  = (half_t*)(ws + (16ull << 20));   // [16,22)
  half_t* Vh   = (half_t*)(ws + (22ull << 20));   // [22,38)  [8192][1024]
  half_t* partH= (half_t*)(ws + (38ull << 20));   // [38,70)  2x16MB
  int8_t* Qi8  = (int8_t*)(ws + (70ull << 20));   // [70,78)
  int8_t* Ki8  = (int8_t*)(ws + (78ull << 20));   // [78,86)
  half_t* Vt   = (half_t*)(ws + (70ull << 20));   // [70,86) after S gemm
  half_t* S    = (half_t*)(ws + (86ull << 20));   // [86,214)
  float* rowpart = (float*)ws;                    // [0,4) after QKV
  float* rinv    = (float*)(ws + (4ull << 20));   // 32 KB

  // 1. X -> fp16
  cast_f32_to_f16<<<(N * D / 4 + 255) / 256, 256, 0, stream>>>(X, Xh, N * D / 4);

  // 2. W -> fp16, transposed
  dim3 tg(D / 64, D / 64);
  transpose_cast<float><<<tg, 256, 0, stream>>>(Wq, D, Wth + 0ull * D * D, D, D, D);
  transpose_cast<float><<<tg, 256, 0, stream>>>(Wk, D, Wth + 1ull * D * D, D, D, D);
  transpose_cast<float><<<tg, 256, 0, stream>>>(Wv, D, Wth + 2ull * D * D, D, D, D);

  // 3. QKV gemm: Q,K -> i8 (scale 32, from f32 acc); V -> Vh fp16
  gemm256<half_t, 2><<<dim3(3 * D / 256, N / 256), 512, 0, stream>>>(
      Xh, D, Wth, D, Vh, D, N, 3 * D, D, 1, 4, nullptr, Qi8, Ki8);

  // 4. P' = exp(Qi8 . Ki8^T * 2^-15)  [8192][8192] fp16  + row partials
  gemm256_i8exp<<<dim3(N / 256, N / 256), 512, 0, stream>>>(
      Qi8, D, Ki8, D, S, N, D, 8, rowpart);

  // 5. rinv = 1 / rowsum
  rowsum_recip<<<(N + 255) / 256, 256, 0, stream>>>(rowpart, rinv, N, 32);

  // 6. Vt = Vh^T  [1024][8192]   (overwrites Qi8/Ki8 — dead after step 4)
  transpose_cast<half_t><<<dim3(D / 64, N / 64), 256, 0, stream>>>(
      Vh, D, Vt, N, N, D);

  // 7. partH = (P' @ Vt^T) * rinv, split-K=2, fp16 partials
  gemm256<half_t, 3><<<dim3(D / 256, 2 * N / 256), 512, 0, stream>>>(
      S, N, Vt, N, partH, D, N, D, N / 2, 2, 4, rinv, nullptr, nullptr);

  // 8. out = part0 + part1
  reduce_add2h<<<(N * D / 8 + 255) / 256, 256, 0, stream>>>(
      (const half8*)partH, (const half8*)(partH + (size_t)N * D), (float4*)out,
      N * D / 8);
}

// Round 12
// 320.141 us; speedup vs baseline: 1.7914x; 1.7914x over previous
//
#include <hip/hip_runtime.h>
#include <hip/hip_fp16.h>
#include <stdint.h>

// SelfAttention: out = softmax((X Wq)(X Wk)^T / 32) (X Wv), N=8192, D=1024.
// R12: revert R11 (sched_barrier pinning = m141 failure mode). Base = R10.
//      (a) PV -> BK=32 / 64KB / 2-phase kernel, byte-identical addressing to
//          the proven i8 kernel (R9's 2-phase conversion gave -24% on S).
//      (b) QKV epilogue writes V directly TRANSPOSED (lane holds 4 consecutive
//          rows of one col -> contiguous 8B stores) -> Vh + transpose deleted.
// Memory map (ws >= 214 MB):
//   [0,16)   Xh (QKV in)     -> rowpart [0,4) + rinv [4,~) after QKV
//   [16,22)  Wth             (dead after QKV)
//   [22,38)  Vt [1024][8192] (QKV epilogue -> PV)
//   [38,70)  partH 2x16MB fp16 (PV -> reduce)
//   [70,78)  Qi8  [78,86) Ki8  (QKV -> S gemm)
//   [86,214) S / P' fp16

typedef _Float16 half_t;
typedef _Float16 half8 __attribute__((ext_vector_type(8)));
typedef _Float16 half4 __attribute__((ext_vector_type(4)));
typedef float f32x4 __attribute__((ext_vector_type(4)));
typedef int i32x4 __attribute__((ext_vector_type(4)));

#define GLOAD16(gp, lp)                                                        \
  __builtin_amdgcn_global_load_lds(                                            \
      (__attribute__((address_space(1))) void*)(gp),                           \
      (__attribute__((address_space(3))) void*)(lp), 16, 0, 0)

#define BAR() __builtin_amdgcn_s_barrier()
#define VMCNT8() asm volatile("s_waitcnt vmcnt(8)")
#define VMCNT4() asm volatile("s_waitcnt vmcnt(4)")
#define VMCNT0() asm volatile("s_waitcnt vmcnt(0)")

// ---------------------------------------------------------------- cast X
__global__ __launch_bounds__(256) void cast_f32_to_f16(
    const float* __restrict__ in, half_t* __restrict__ out, int n4) {
  int i = blockIdx.x * 256 + threadIdx.x;
  if (i < n4) {
    float4 v = ((const float4*)in)[i];
    half4 o = {(half_t)v.x, (half_t)v.y, (half_t)v.z, (half_t)v.w};
    ((half4*)out)[i] = o;
  }
}

// ------------------------------------------------- cast + transpose (f32->fp16)
template <typename Tin>
__global__ __launch_bounds__(256) void transpose_cast(
    const Tin* __restrict__ in, int ldin, half_t* __restrict__ out, int ldout,
    int R, int C) {
  __shared__ half_t tile[64][65];
  const int c0 = blockIdx.x * 64, r0 = blockIdx.y * 64;
  const int tx = threadIdx.x & 63, ty = threadIdx.x >> 6;
#pragma unroll
  for (int i = 0; i < 16; i++) {
    int r = ty * 16 + i;
    tile[r][tx] = (half_t)in[(size_t)(r0 + r) * ldin + c0 + tx];
  }
  __syncthreads();
#pragma unroll
  for (int i = 0; i < 16; i++) {
    int c = ty * 16 + i;
    out[(size_t)(c0 + c) * ldout + r0 + tx] = tile[tx][c];
  }
}

// ---------------------------------------------------------- rowsum reciprocal
__global__ __launch_bounds__(256) void rowsum_recip(
    const float* __restrict__ rowpart, float* __restrict__ rinv, int rows,
    int w4) {
  int r = blockIdx.x * 256 + threadIdx.x;
  if (r < rows) {
    const float4* p = (const float4*)(rowpart + (size_t)r * (w4 * 4));
    float s = 0.f;
    for (int i = 0; i < w4; i++) {
      float4 v = p[i];
      s += v.x + v.y + v.z + v.w;
    }
    rinv[r] = 1.f / s;
  }
}

// ------------------------------------------------- reduce (fp16 partials add)
__global__ __launch_bounds__(256) void reduce_add2h(
    const half8* __restrict__ a, const half8* __restrict__ b,
    float4* __restrict__ o, int n8) {
  int i = blockIdx.x * 256 + threadIdx.x;
  if (i < n8) {
    half8 x = a[i], y = b[i];
    float4 o0, o1;
    o0.x = (float)x[0] + (float)y[0];
    o0.y = (float)x[1] + (float)y[1];
    o0.z = (float)x[2] + (float)y[2];
    o0.w = (float)x[3] + (float)y[3];
    o1.x = (float)x[4] + (float)y[4];
    o1.y = (float)x[5] + (float)y[5];
    o1.z = (float)x[6] + (float)y[6];
    o1.w = (float)x[7] + (float)y[7];
    o[2 * i] = o0;
    o[2 * i + 1] = o1;
  }
}

// ============================================================ fp16 256^2 GEMM (QKV)
// MODE 2: bx<4: Qi8, bx<8: Ki8 (scale 32, from f32 acc); bx>=8: V written
// TRANSPOSED to C=Vt[1024][8192] (ldc=8192): lane's 4 acc rows of one col
// are contiguous in Vt -> half4 stores. (R10's 4-phase BK=64 structure.)
template <typename To, int MODE>
__global__ __launch_bounds__(512, 2) void gemm256(
    const half_t* __restrict__ A, int lda, const half_t* __restrict__ Bt,
    int ldb, To* __restrict__ C, int ldc, int M, int N, int K, int ychunks,
    int SG, const float* __restrict__ rinv, int8_t* __restrict__ qi8,
    int8_t* __restrict__ ki8) {
  __shared__ __align__(16) char sm[131072];

  const int t = threadIdx.x;
  const int w = t >> 6;
  const int ln = t & 63;

  const int nwg = gridDim.x * gridDim.y;
  const int bid = blockIdx.y * gridDim.x + blockIdx.x;
  const int cpx = nwg >> 3;
  const int q = (bid & 7) * cpx + (bid >> 3);
  const int tiles_y = gridDim.y / ychunks;
  const int per_chunk = gridDim.x * tiles_y;
  const int chunk = q / per_chunk;
  int r_ = q - chunk * per_chunk;
  const int sw = SG * tiles_y;
  const int s_ = r_ / sw;
  r_ -= s_ * sw;
  const int by = r_ / SG;
  const int bx = s_ * SG + (r_ - by * SG);

  A += (size_t)chunk * K;
  Bt += (size_t)chunk * K;
  C += (size_t)chunk * M * ldc;

  const int row0 = by * 256;
  const int col0 = bx * 256;

  const int srow = w * 8 + (ln >> 3);
  const int sslot = (ln & 7) ^ ((ln >> 3) & 7);
  const half_t* Ag = A + (size_t)(row0 + srow) * lda + sslot * 8;
  const half_t* Bg = Bt + (size_t)(col0 + srow) * ldb + sslot * 8;
  const int ldsw = w * 1024;

#define STAGE_AB(kt, bb)                                                       \
  do {                                                                         \
    const half_t* ga_ = Ag + (size_t)(kt) * 64;                                \
    const half_t* gb_ = Bg + (size_t)(kt) * 64;                                \
    GLOAD16(ga_, sm + (bb) + ldsw);                                            \
    GLOAD16(ga_ + 64 * (size_t)lda, sm + (bb) + 8192 + ldsw);                  \
    GLOAD16(ga_ + 128 * (size_t)lda, sm + (bb) + 16384 + ldsw);                \
    GLOAD16(ga_ + 192 * (size_t)lda, sm + (bb) + 24576 + ldsw);                \
    GLOAD16(gb_, sm + (bb) + 32768 + ldsw);                                    \
    GLOAD16(gb_ + 64 * (size_t)ldb, sm + (bb) + 40960 + ldsw);                 \
    GLOAD16(gb_ + 128 * (size_t)ldb, sm + (bb) + 49152 + ldsw);                \
    GLOAD16(gb_ + 192 * (size_t)ldb, sm + (bb) + 57344 + ldsw);                \
  } while (0)

  const int wr = w >> 2;
  const int wc = w & 3;
  const int fr = ln & 15;
  const int kg = ln >> 4;
  const int sx0 = ((kg ^ (fr & 7)) << 4);
  const int sx1 = sx0 ^ 64;
  const int arow = (wr * 128 + fr) * 128;
  const int brow = 32768 + (wc * 64 + fr) * 128;

#define READ_A(MI0, cb)                                                        \
  _Pragma("unroll") for (int mi = 0; mi < 4; mi++) {                           \
    a4[mi][0] = *(const half8*)(sm + (cb) + arow + (MI0 + mi) * 2048 + sx0);   \
    a4[mi][1] = *(const half8*)(sm + (cb) + arow + (MI0 + mi) * 2048 + sx1);   \
  }
#define READ_B(NI, cb)                                                         \
  do {                                                                         \
    b8[NI][0] = *(const half8*)(sm + (cb) + brow + (NI) * 2048 + sx0);         \
    b8[NI][1] = *(const half8*)(sm + (cb) + brow + (NI) * 2048 + sx1);         \
  } while (0)

#define MFMA_Q(MI0, NI0)                                                       \
  __builtin_amdgcn_s_setprio(1);                                               \
  _Pragma("unroll") for (int kk = 0; kk < 2; kk++)                             \
  _Pragma("unroll") for (int mi = 0; mi < 4; mi++)                             \
  _Pragma("unroll") for (int ni = 0; ni < 2; ni++)                             \
      acc[MI0 + mi][NI0 + ni] = __builtin_amdgcn_mfma_f32_16x16x32_f16(        \
          a4[mi][kk], b8[NI0 + ni][kk], acc[MI0 + mi][NI0 + ni], 0, 0, 0);     \
  __builtin_amdgcn_s_setprio(0);

  half8 a4[4][2], b8[4][2];
  f32x4 acc[8][4] = {};

  const int NT = K >> 6;

  STAGE_AB(0, 0);
  STAGE_AB(1, 65536);
  VMCNT8();
  BAR();

#define TILE(tt, cb)                                                           \
  do {                                                                         \
    READ_A(0, cb);                                                             \
    READ_B(0, cb);                                                             \
    READ_B(1, cb);                                                             \
    BAR();                                                                     \
    MFMA_Q(0, 0);                                                              \
    BAR();                                                                     \
    READ_B(2, cb);                                                             \
    READ_B(3, cb);                                                             \
    BAR();                                                                     \
    MFMA_Q(0, 2);                                                              \
    BAR();                                                                     \
    READ_A(4, cb);                                                             \
    BAR();                                                                     \
    MFMA_Q(4, 2);                                                              \
    BAR();                                                                     \
    if ((tt) + 2 < NT) {                                                       \
      STAGE_AB((tt) + 2, cb);                                                  \
      VMCNT8();                                                                \
    } else {                                                                   \
      VMCNT0();                                                                \
    }                                                                          \
    BAR();                                                                     \
    MFMA_Q(4, 0);                                                              \
    BAR();                                                                     \
  } while (0)

  for (int kt = 0; kt < NT; kt += 2) {
    TILE(kt, 0);
    TILE(kt + 1, 65536);
  }

  // ---- epilogue: C/D layout col = lane&15, row = (lane>>4)*4 + j ----
  const int orow = row0 + wr * 128 + (ln >> 4) * 4;
  const int ocol = col0 + wc * 64 + (ln & 15);
  if constexpr (MODE == 2) {
    if (bx < 8) {  // Q or K -> i8 (scale 32)
      int8_t* qk = bx < 4 ? qi8 : ki8;
      const int cbase = ocol - (bx < 4 ? 0 : 1024);
#pragma unroll
      for (int mi = 0; mi < 8; mi++)
#pragma unroll
        for (int j = 0; j < 4; j++) {
          const size_t r = orow + mi * 16 + j;
#pragma unroll
          for (int ni = 0; ni < 4; ni++) {
            float f = acc[mi][ni][j] * 32.f;
            f = fminf(fmaxf(f, -127.f), 127.f);
            qk[r * 1024 + cbase + ni * 16] = (int8_t)rintf(f);
          }
        }
    } else {  // V -> Vt transposed: Vt[c][r..r+3] = acc[mi][ni][0..3]
#pragma unroll
      for (int mi = 0; mi < 8; mi++)
#pragma unroll
        for (int ni = 0; ni < 4; ni++) {
          const int c = ocol - 2048 + ni * 16;
          half4 v = {(half_t)acc[mi][ni][0], (half_t)acc[mi][ni][1],
                     (half_t)acc[mi][ni][2], (half_t)acc[mi][ni][3]};
          *(half4*)(C + (size_t)c * ldc + orow + mi * 16) = v;
        }
    }
  } else {
#pragma unroll
    for (int mi = 0; mi < 8; mi++)
#pragma unroll
      for (int ni = 0; ni < 4; ni++) {
        To* cp = C + (size_t)(orow + mi * 16) * ldc + ocol + ni * 16;
#pragma unroll
        for (int j = 0; j < 4; j++) cp[(size_t)j * ldc] = (To)acc[mi][ni][j];
      }
  }
#undef TILE
#undef MFMA_Q
#undef READ_A
#undef READ_B
#undef STAGE_AB
}

// ===================================================== fp16 BK=32 2-phase (PV)
// partH = (A @ Bt^T) * rinv[r], fp16. Byte-identical addressing/swizzle/
// barrier structure to the proven i8 kernel (64B LDS rows, 64KB total).
__global__ __launch_bounds__(512, 2) void gemm256_h32(
    const half_t* __restrict__ A, int lda, const half_t* __restrict__ Bt,
    int ldb, half_t* __restrict__ C, int ldc, int M, int K, int ychunks,
    int SG, const float* __restrict__ rinv) {
  __shared__ __align__(16) char sm[65536];

  const int t = threadIdx.x;
  const int w = t >> 6;
  const int ln = t & 63;

  const int nwg = gridDim.x * gridDim.y;
  const int bid = blockIdx.y * gridDim.x + blockIdx.x;
  const int cpx = nwg >> 3;
  const int q = (bid & 7) * cpx + (bid >> 3);
  const int tiles_y = gridDim.y / ychunks;
  const int per_chunk = gridDim.x * tiles_y;
  const int chunk = q / per_chunk;
  int r_ = q - chunk * per_chunk;
  const int sw = SG * tiles_y;
  const int s_ = r_ / sw;
  r_ -= s_ * sw;
  const int by = r_ / SG;
  const int bx = s_ * SG + (r_ - by * SG);

  A += (size_t)chunk * K;
  Bt += (size_t)chunk * K;
  C += (size_t)chunk * M * ldc;

  const int row0 = by * 256;
  const int col0 = bx * 256;

  // staging: 4 gloads/tile; row rt (+128), 16B slot ln&3, pre-swizzled source
  const int rt = w * 16 + (ln >> 2);
  const int sl = (ln & 3) ^ ((rt >> 1) & 3);
  const half_t* Ag = A + (size_t)(row0 + rt) * lda + sl * 8;
  const half_t* Bg = Bt + (size_t)(col0 + rt) * ldb + sl * 8;
  const int ldsw = w * 1024;

#define STAGEH(kt, bb)                                                         \
  do {                                                                         \
    const half_t* ga_ = Ag + (size_t)(kt) * 32;                                \
    const half_t* gb_ = Bg + (size_t)(kt) * 32;                                \
    GLOAD16(ga_, sm + (bb) + ldsw);                                            \
    GLOAD16(ga_ + 128 * (size_t)lda, sm + (bb) + 8192 + ldsw);                 \
    GLOAD16(gb_, sm + (bb) + 16384 + ldsw);                                    \
    GLOAD16(gb_ + 128 * (size_t)ldb, sm + (bb) + 24576 + ldsw);                \
  } while (0)

  // fragment reads: lane fr, k-halfs [kg*8, kg*8+8) = 16B slot kg (swizzled)
  const int wr = w >> 2;
  const int wc = w & 3;
  const int fr = ln & 15;
  const int kg = ln >> 4;
  const int sx = (kg ^ ((fr >> 1) & 3)) << 4;
  const int arow = (wr * 128 + fr) * 64;
  const int brow = 16384 + (wc * 64 + fr) * 64;

#define RDH_A(MI0, cb)                                                         \
  _Pragma("unroll") for (int mi = 0; mi < 4; mi++)                             \
      ah[mi] = *(const half8*)(sm + (cb) + arow + ((MI0) + mi) * 1024 + sx);
#define RDH_B(NI, cb)                                                          \
  bh[NI] = *(const half8*)(sm + (cb) + brow + (NI) * 1024 + sx);

#define MMH_Q(MI0, NI0)                                                        \
  __builtin_amdgcn_s_setprio(1);                                               \
  _Pragma("unroll") for (int mi = 0; mi < 4; mi++)                             \
  _Pragma("unroll") for (int ni = 0; ni < 2; ni++)                             \
      acc[(MI0) + mi][(NI0) + ni] = __builtin_amdgcn_mfma_f32_16x16x32_f16(    \
          ah[mi], bh[(NI0) + ni], acc[(MI0) + mi][(NI0) + ni], 0, 0, 0);       \
  __builtin_amdgcn_s_setprio(0);

  half8 ah[4], bh[4];
  f32x4 acc[8][4] = {};

  const int NT = K >> 5;  // BK=32 -> 128 tiles at K=4096 (even)

  STAGEH(0, 0);
  STAGEH(1, 32768);
  VMCNT4();
  BAR();

#define TILEH(tt, cb)                                                          \
  do {                                                                         \
    /* P1 */                                                                   \
    RDH_A(0, cb);                                                              \
    RDH_B(0, cb);                                                              \
    RDH_B(1, cb);                                                              \
    RDH_B(2, cb);                                                              \
    RDH_B(3, cb);                                                              \
    MMH_Q(0, 0);                                                               \
    MMH_Q(0, 2);                                                               \
    /* P2 */                                                                   \
    RDH_A(4, cb);                                                              \
    MMH_Q(4, 2);                                                               \
    BAR(); /* all cb reads consumed above (in-order lgkm) */                   \
    if ((tt) + 2 < NT) {                                                       \
      STAGEH((tt) + 2, cb);                                                    \
      MMH_Q(4, 0);                                                             \
      VMCNT4(); /* t+1's 4 loads landed; t+2's in flight */                    \
    } else {                                                                   \
      MMH_Q(4, 0);                                                             \
      VMCNT0();                                                                \
    }                                                                          \
    BAR(); /* next buffer published */                                         \
  } while (0)

  for (int kt = 0; kt < NT; kt += 2) {
    TILEH(kt, 0);
    TILEH(kt + 1, 32768);
  }

  // ---- epilogue: (acc * rinv[r]) -> fp16 ----
  const int orow = row0 + wr * 128 + (ln >> 4) * 4;
  const int ocol = col0 + wc * 64 + (ln & 15);
#pragma unroll
  for (int mi = 0; mi < 8; mi++)
#pragma unroll
    for (int j = 0; j < 4; j++) {
      const size_t r = orow + mi * 16 + j;
      const float s = rinv[r];
#pragma unroll
      for (int ni = 0; ni < 4; ni++)
        C[r * ldc + ocol + ni * 16] = (half_t)(acc[mi][ni][j] * s);
    }
#undef TILEH
#undef MMH_Q
#undef RDH_A
#undef RDH_B
#undef STAGEH
}

// ============================================================ i8 256^2 S-GEMM
// P' = exp((A i8dot Bt) * 2^-15) fp16 + row partials. 2 phases/tile (R10).
__global__ __launch_bounds__(512, 2) void gemm256_i8exp(
    const int8_t* __restrict__ A, int lda, const int8_t* __restrict__ Bt,
    int ldb, half_t* __restrict__ C, int ldc, int K, int SG,
    float* __restrict__ rowpart) {
  __shared__ __align__(16) char sm[65536];

  const int t = threadIdx.x;
  const int w = t >> 6;
  const int ln = t & 63;

  const int nwg = gridDim.x * gridDim.y;
  const int bid = blockIdx.y * gridDim.x + blockIdx.x;
  const int cpx = nwg >> 3;
  const int q = (bid & 7) * cpx + (bid >> 3);
  const int sw = SG * gridDim.y;
  const int s_ = q / sw;
  int r_ = q - s_ * sw;
  const int by = r_ / SG;
  const int bx = s_ * SG + (r_ - by * SG);

  const int row0 = by * 256;
  const int col0 = bx * 256;

  const int rt = w * 16 + (ln >> 2);
  const int sl = (ln & 3) ^ ((rt >> 1) & 3);
  const int8_t* Ag = A + (size_t)(row0 + rt) * lda + sl * 16;
  const int8_t* Bg = Bt + (size_t)(col0 + rt) * ldb + sl * 16;
  const int ldsw = w * 1024;

#define STAGE8(kt, bb)                                                         \
  do {                                                                         \
    const int8_t* ga_ = Ag + (size_t)(kt) * 64;                                \
    const int8_t* gb_ = Bg + (size_t)(kt) * 64;                                \
    GLOAD16(ga_, sm + (bb) + ldsw);                                            \
    GLOAD16(ga_ + 128 * (size_t)lda, sm + (bb) + 8192 + ldsw);                 \
    GLOAD16(gb_, sm + (bb) + 16384 + ldsw);                                    \
    GLOAD16(gb_ + 128 * (size_t)ldb, sm + (bb) + 24576 + ldsw);                \
  } while (0)

  const int wr = w >> 2;
  const int wc = w & 3;
  const int fr = ln & 15;
  const int kg = ln >> 4;
  const int sx = (kg ^ ((fr >> 1) & 3)) << 4;
  const int arow = (wr * 128 + fr) * 64;
  const int brow = 16384 + (wc * 64 + fr) * 64;

#define READ_A8(MI0, cb)                                                       \
  _Pragma("unroll") for (int mi = 0; mi < 4; mi++)                             \
      a8[mi] = *(const i32x4*)(sm + (cb) + arow + (MI0 + mi) * 1024 + sx);
#define READ_B8(NI, cb)                                                        \
  b8v[NI] = *(const i32x4*)(sm + (cb) + brow + (NI) * 1024 + sx);

#define MFMA_Q8(MI0, NI0)                                                      \
  __builtin_amdgcn_s_setprio(1);                                               \
  _Pragma("unroll") for (int mi = 0; mi < 4; mi++)                             \
  _Pragma("unroll") for (int ni = 0; ni < 2; ni++)                             \
      acc[MI0 + mi][NI0 + ni] = __builtin_amdgcn_mfma_i32_16x16x64_i8(         \
          a8[mi], b8v[NI0 + ni], acc[MI0 + mi][NI0 + ni], 0, 0, 0);            \
  __builtin_amdgcn_s_setprio(0);

  i32x4 a8[4], b8v[4];
  i32x4 acc[8][4] = {};

  const int NT = K >> 6;  // 16

  STAGE8(0, 0);
  STAGE8(1, 32768);
  VMCNT4();
  BAR();

#define TILE8(tt, cb)                                                          \
  do {                                                                         \
    /* P1 */                                                                   \
    READ_A8(0, cb);                                                            \
    READ_B8(0, cb);                                                            \
    READ_B8(1, cb);                                                            \
    READ_B8(2, cb);                                                            \
    READ_B8(3, cb);                                                            \
    MFMA_Q8(0, 0);                                                             \
    MFMA_Q8(0, 2);                                                             \
    /* P2 */                                                                   \
    READ_A8(4, cb);                                                            \
    MFMA_Q8(4, 2);                                                             \
    BAR(); /* all reads of cb consumed by MFMAs above (in-order lgkm) */       \
    if ((tt) + 2 < NT) {                                                       \
      STAGE8((tt) + 2, cb);                                                    \
      MFMA_Q8(4, 0);                                                           \
      VMCNT4(); /* t+1's 4 loads landed; t+2's in flight */                    \
    } else {                                                                   \
      MFMA_Q8(4, 0);                                                           \
      VMCNT0();                                                                \
    }                                                                          \
    BAR(); /* next buffer published to all waves */                            \
  } while (0)

  for (int kt = 0; kt < NT; kt += 2) {
    TILE8(kt, 0);
    TILE8(kt + 1, 32768);
  }

  // ---- epilogue: s = acc * 2^-15 (scale 32*32 quant, /32 softmax) ----
  const int orow = row0 + wr * 128 + (ln >> 4) * 4;
  const int ocol = col0 + wc * 64 + (ln & 15);
  const float sc = 3.0517578125e-5f;  // 1/32768
  const int rp_ld = gridDim.x * 4;
#pragma unroll
  for (int mi = 0; mi < 8; mi++) {
#pragma unroll
    for (int j = 0; j < 4; j++) {
      const int r = orow + mi * 16 + j;
      float s = 0.f;
#pragma unroll
      for (int ni = 0; ni < 4; ni++) {
        float e = __expf((float)acc[mi][ni][j] * sc);
        C[(size_t)r * ldc + ocol + ni * 16] = (half_t)e;
        s += e;
      }
      s += __shfl_xor(s, 1);
      s += __shfl_xor(s, 2);
      s += __shfl_xor(s, 4);
      s += __shfl_xor(s, 8);
      if ((ln & 15) == 0) rowpart[(size_t)r * rp_ld + bx * 4 + wc] = s;
    }
  }
#undef TILE8
#undef MFMA_Q8
#undef READ_A8
#undef READ_B8
#undef STAGE8
}

// ---------------------------------------------------------------- launch
extern "C" void kernel_launch(void* const* d_in, const int* in_sizes, int n_in,
                              void* d_out, int out_size, void* d_ws,
                              size_t ws_size, hipStream_t stream) {
  const float* X = (const float*)d_in[0];
  const float* Wq = (const float*)d_in[1];
  const float* Wk = (const float*)d_in[2];
  const float* Wv = (const float*)d_in[3];
  float* out = (float*)d_out;

  const int N = 8192, D = 1024;

  char* ws = (char*)d_ws;
  half_t* Xh   = (half_t*)(ws);                   // [0,16)
  half_t* Wth  = (half_t*)(ws + (16ull << 20));   // [16,22)
  half_t* Vt   = (half_t*)(ws + (22ull << 20));   // [22,38)  [1024][8192]
  half_t* partH= (half_t*)(ws + (38ull << 20));   // [38,70)  2x16MB
  int8_t* Qi8  = (int8_t*)(ws + (70ull << 20));   // [70,78)
  int8_t* Ki8  = (int8_t*)(ws + (78ull << 20));   // [78,86)
  half_t* S    = (half_t*)(ws + (86ull << 20));   // [86,214)
  float* rowpart = (float*)ws;                    // [0,4) after QKV
  float* rinv    = (float*)(ws + (4ull << 20));   // 32 KB

  // 1. X -> fp16
  cast_f32_to_f16<<<(N * D / 4 + 255) / 256, 256, 0, stream>>>(X, Xh, N * D / 4);

  // 2. W -> fp16, transposed
  dim3 tg(D / 64, D / 64);
  transpose_cast<float><<<tg, 256, 0, stream>>>(Wq, D, Wth + 0ull * D * D, D, D, D);
  transpose_cast<float><<<tg, 256, 0, stream>>>(Wk, D, Wth + 1ull * D * D, D, D, D);
  transpose_cast<float><<<tg, 256, 0, stream>>>(Wv, D, Wth + 2ull * D * D, D, D, D);

  // 3. QKV gemm: Q,K -> i8 (scale 32); V -> Vt (transposed direct)
  gemm256<half_t, 2><<<dim3(3 * D / 256, N / 256), 512, 0, stream>>>(
      Xh, D, Wth, D, Vt, N, N, 3 * D, D, 1, 4, nullptr, Qi8, Ki8);

  // 4. P' = exp(Qi8 . Ki8^T * 2^-15)  [8192][8192] fp16  + row partials
  gemm256_i8exp<<<dim3(N / 256, N / 256), 512, 0, stream>>>(
      Qi8, D, Ki8, D, S, N, D, 8, rowpart);

  // 5. rinv = 1 / rowsum
  rowsum_recip<<<(N + 255) / 256, 256, 0, stream>>>(rowpart, rinv, N, 32);

  // 6. partH = (P' @ Vt^T) * rinv, split-K=2, BK32 2-phase
  gemm256_h32<<<dim3(D / 256, 2 * N / 256), 512, 0, stream>>>(
      S, N, Vt, N, partH, D, N, N / 2, 2, 4, rinv);

  // 7. out = part0 + part1
  reduce_add2h<<<(N * D / 8 + 255) / 256, 256, 0, stream>>>(
      (const half8*)partH, (const half8*)(partH + (size_t)N * D), (float4*)out,
      N * D / 8);
}